// Round 13
// baseline (86.022 us; speedup 1.0000x reference)
//
#include <hip/hip_runtime.h>
#include <hip/hip_bf16.h>
#include <stdint.h>

#define N_NODES   50000
#define K_DIM     128
#define OUT_DIM   32
#define N_EDGES   1600000
#define NBKT      782                         // 64-node coarse buckets
#define CAP       3072                        // fixed window stride (mean 2046 + 22 sigma)
#define AFIT      16                          // edges per thread in fill
#define ABLK      ((N_EDGES + 256*AFIT - 1) / (256*AFIT))   // 391

// -------- K1: h = x @ W -> bf16; 64 rows/block, 8 MACs per LDS read ---------
// thread (col = t&31, rg = t>>5) computes rows rg*8..rg*8+7 of one column:
// each wlds read feeds 8 FMAs -> LDS-pipe time ~4 us (was ~30), VALU-bound.
__global__ __launch_bounds__(256) void gemm_kernel(const float* __restrict__ x,
                                                   const float* __restrict__ w,
                                                   __hip_bfloat16* __restrict__ h,
                                                   int* __restrict__ cursor) {
    __shared__ float wlds[K_DIM * OUT_DIM];
    const int t = threadIdx.x;
    if (blockIdx.x == 0) {
        for (int i = t; i < NBKT; i += 256) cursor[i] = 0;
    }
    #pragma unroll
    for (int i = 0; i < (K_DIM * OUT_DIM) / 256; ++i)
        wlds[i * 256 + t] = w[i * 256 + t];
    __syncthreads();

    const int col  = t & 31;
    const int rg   = t >> 5;
    const int row0 = blockIdx.x * 64 + rg * 8;

    const float4* xp[8];
    #pragma unroll
    for (int r = 0; r < 8; ++r) {
        int row = row0 + r;
        if (row >= N_NODES) row = N_NODES - 1;   // clamp (loads only; store guarded)
        xp[r] = reinterpret_cast<const float4*>(x + (size_t)row * K_DIM);
    }

    float acc[8] = {0.f, 0.f, 0.f, 0.f, 0.f, 0.f, 0.f, 0.f};
    #pragma unroll 2
    for (int k4 = 0; k4 < K_DIM / 4; ++k4) {
        const int k = k4 * 4;
        const float w0 = wlds[(k + 0) * OUT_DIM + col];
        const float w1 = wlds[(k + 1) * OUT_DIM + col];
        const float w2 = wlds[(k + 2) * OUT_DIM + col];
        const float w3 = wlds[(k + 3) * OUT_DIM + col];
        #pragma unroll
        for (int r = 0; r < 8; ++r) {
            const float4 xv = xp[r][k4];
            acc[r] += xv.x * w0 + xv.y * w1 + xv.z * w2 + xv.w * w3;
        }
    }
    #pragma unroll
    for (int r = 0; r < 8; ++r) {
        const int row = row0 + r;
        if (row < N_NODES)
            h[(size_t)row * OUT_DIM + col] = __float2bfloat16(acc[r]);
    }
}

// -------- K2: scatter edges into fixed-stride windows; single LDS-atomic pass
__global__ __launch_bounds__(256) void fill_direct(const int*   __restrict__ esrc,
                                                   const int*   __restrict__ edst,
                                                   const float* __restrict__ ew,
                                                   int*         __restrict__ cursor,
                                                   uint64_t*    __restrict__ pairs) {
    __shared__ int cnt[NBKT];
    __shared__ int wbase[NBKT];
    const int t = threadIdx.x;
    for (int i = t; i < NBKT; i += 256) cnt[i] = 0;
    __syncthreads();

    uint32_t lo[AFIT], hi[AFIT];
    uint16_t rk[AFIT];                         // rank within block (< 4096)
    const int base = blockIdx.x * 256 * AFIT;
    #pragma unroll
    for (int k = 0; k < AFIT; ++k) {
        const int e = base + k * 256 + t;
        if (e < N_EDGES) {
            const uint32_t s = (uint32_t)esrc[e];
            const uint32_t d = (uint32_t)edst[e];
            lo[k] = (d << 16) | s;             // dst:16 | src:16
            hi[k] = __float_as_uint(ew[e]);
            rk[k] = (uint16_t)atomicAdd(&cnt[d >> 6], 1);   // count AND rank
        } else {
            lo[k] = 0xffffffffu;
        }
    }
    __syncthreads();
    for (int i = t; i < NBKT; i += 256) {
        const int c = cnt[i];
        if (c) wbase[i] = atomicAdd(&cursor[i], c);
    }
    __syncthreads();
    #pragma unroll
    for (int k = 0; k < AFIT; ++k) {
        if (lo[k] != 0xffffffffu) {
            const int b   = (int)(lo[k] >> 22);             // dst >> 6
            const int pos = wbase[b] + (int)rk[k];
            if (pos < CAP)                                  // overflow guard (P ~ 0)
                pairs[(size_t)b * CAP + pos] = ((uint64_t)hi[k] << 32) | lo[k];
        }
    }
}

// -------- K3: fused sort+pull per bucket (R12-proven) -----------------------
__global__ __launch_bounds__(512) void sort_pull(const int*      __restrict__ cursor,
                                                 const uint64_t* __restrict__ pairs,
                                                 const __hip_bfloat16* __restrict__ h,
                                                 float*          __restrict__ out) {
    __shared__ uint64_t stg[CAP];             // 24 KB
    __shared__ int lcnt[64];
    __shared__ int loff[65];
    const int b    = blockIdx.x;
    const int t    = threadIdx.x;
    const size_t beg = (size_t)b * CAP;
    const int cnt  = min(cursor[b], CAP);
    const int wv   = t >> 6;                  // 8 waves
    const int lane = t & 63;
    const int col  = lane & 31;
    const int half = lane >> 5;

    if (t < 64) lcnt[t] = 0;
    __syncthreads();

    for (int i = t; i < cnt; i += 512)
        atomicAdd(&lcnt[(int)((pairs[beg + i] >> 16) & 63)], 1);
    __syncthreads();
    if (t == 0) {
        int run = 0;
        #pragma unroll
        for (int i = 0; i < 64; ++i) { loff[i] = run; run += lcnt[i]; }
        loff[64] = run;
    }
    __syncthreads();
    if (t < 64) lcnt[t] = loff[t];            // cursor
    __syncthreads();
    for (int i = t; i < cnt; i += 512) {
        const uint64_t p = pairs[beg + i];
        const int pos = atomicAdd(&lcnt[(int)((p >> 16) & 63)], 1);
        stg[pos] = p;
    }
    __syncthreads();
    for (int nl = wv * 8; nl < wv * 8 + 8; ++nl) {
        const int node = (b << 6) + nl;
        if (node >= N_NODES) break;
        const int jb = loff[nl], je = loff[nl + 1];
        float acc = 0.f;
        int j = jb + half;
        for (; j + 6 < je; j += 8) {
            const uint64_t p0 = stg[j];
            const uint64_t p1 = stg[j + 2];
            const uint64_t p2 = stg[j + 4];
            const uint64_t p3 = stg[j + 6];
            const float a0 = __bfloat162float(h[(size_t)(p0 & 0xffffu) * OUT_DIM + col]);
            const float a1 = __bfloat162float(h[(size_t)(p1 & 0xffffu) * OUT_DIM + col]);
            const float a2 = __bfloat162float(h[(size_t)(p2 & 0xffffu) * OUT_DIM + col]);
            const float a3 = __bfloat162float(h[(size_t)(p3 & 0xffffu) * OUT_DIM + col]);
            acc += __uint_as_float((uint32_t)(p0 >> 32)) * a0;
            acc += __uint_as_float((uint32_t)(p1 >> 32)) * a1;
            acc += __uint_as_float((uint32_t)(p2 >> 32)) * a2;
            acc += __uint_as_float((uint32_t)(p3 >> 32)) * a3;
        }
        for (; j < je; j += 2) {
            const uint64_t p = stg[j];
            acc += __uint_as_float((uint32_t)(p >> 32)) *
                   __bfloat162float(h[(size_t)(p & 0xffffu) * OUT_DIM + col]);
        }
        acc += __shfl_xor(acc, 32, 64);
        if (half == 0) out[(size_t)node * OUT_DIM + col] = acc;
    }
}

// -------- fallback: atomic scatter (bf16 h) --------
__global__ __launch_bounds__(256) void scatter_kernel(const int*   __restrict__ esrc,
                                                      const int*   __restrict__ edst,
                                                      const float* __restrict__ ew,
                                                      const __hip_bfloat16* __restrict__ h,
                                                      float*       out) {
    const long long gid = (long long)blockIdx.x * blockDim.x + threadIdx.x;
    const int e   = (int)(gid >> 5);
    const int col = (int)(gid & 31);
    if (e >= N_EDGES) return;
    atomicAdd(out + (size_t)edst[e] * OUT_DIM + col,
              ew[e] * __bfloat162float(h[(size_t)esrc[e] * OUT_DIM + col]));
}

extern "C" void kernel_launch(void* const* d_in, const int* in_sizes, int n_in,
                              void* d_out, int out_size, void* d_ws, size_t ws_size,
                              hipStream_t stream) {
    const float* x    = (const float*)d_in[0];
    const float* w    = (const float*)d_in[1];
    const int*   esrc = (const int*)d_in[2];
    const int*   edst = (const int*)d_in[3];
    const float* ew   = (const float*)d_in[4];
    float*       out  = (float*)d_out;

    const size_t PAIRS_B = (size_t)NBKT * CAP * 8;         // 19,218,432
    const size_t H_B     = (size_t)N_NODES * OUT_DIM * 2;  //  3,200,000 (bf16)
    const size_t CUR_B   = (size_t)NBKT * 4;               //      3,128
    const size_t REQ     = PAIRS_B + H_B + CUR_B;

    uint64_t*        pairs  = (uint64_t*)d_ws;
    __hip_bfloat16*  h      = (__hip_bfloat16*)((char*)d_ws + PAIRS_B);
    int*             cursor = (int*)((char*)d_ws + PAIRS_B + H_B);

    if (ws_size >= REQ) {
        gemm_kernel<<<(N_NODES + 63) / 64, 256, 0, stream>>>(x, w, h, cursor);
        fill_direct<<<ABLK, 256, 0, stream>>>(esrc, edst, ew, cursor, pairs);
        sort_pull<<<NBKT, 512, 0, stream>>>(cursor, pairs, h, out);
    } else {
        __hip_bfloat16* hf = (__hip_bfloat16*)d_ws;
        int* cur = (int*)((char*)d_ws + H_B);
        (void)hipMemsetAsync(d_out, 0, (size_t)out_size * sizeof(float), stream);
        gemm_kernel<<<(N_NODES + 63) / 64, 256, 0, stream>>>(x, w, hf, cur);
        const long long total = (long long)N_EDGES * OUT_DIM;
        scatter_kernel<<<(int)((total + 255) / 256), 256, 0, stream>>>(esrc, edst, ew, hf, out);
    }
}

// Round 14
// 81.964 us; speedup vs baseline: 1.0495x; 1.0495x over previous
//
#include <hip/hip_runtime.h>
#include <hip/hip_bf16.h>
#include <stdint.h>

#define N_NODES   50000
#define K_DIM     128
#define OUT_DIM   32
#define N_EDGES   1600000
#define NBKT      782                         // 64-node coarse buckets
#define CAP       3072                        // fixed window stride (mean 2046 + 22 sigma)
#define AFIT      16                          // edges per thread in fill
#define ABLK      ((N_EDGES + 256*AFIT - 1) / (256*AFIT))   // 391

// -------- K1: h = x @ W -> bf16; 32 rows/block, 4 rows/thread ---------------
// LDS reads/FMA = 1/4 (7.5 us pipe total) while keeping 1563 blocks (~6
// waves/SIMD) for latency hiding — the middle point between R12 (1 row/thread,
// LDS-bound 30 us) and R13 (8 rows/thread, 782 blocks, latency-bound 42 us).
__global__ __launch_bounds__(256) void gemm_kernel(const float* __restrict__ x,
                                                   const float* __restrict__ w,
                                                   __hip_bfloat16* __restrict__ h,
                                                   int* __restrict__ cursor) {
    __shared__ float wlds[K_DIM * OUT_DIM];
    const int t = threadIdx.x;
    if (blockIdx.x == 0) {
        for (int i = t; i < NBKT; i += 256) cursor[i] = 0;
    }
    #pragma unroll
    for (int i = 0; i < (K_DIM * OUT_DIM) / 256; ++i)
        wlds[i * 256 + t] = w[i * 256 + t];
    __syncthreads();

    const int col  = t & 31;
    const int rg   = t >> 5;                  // 8 row-groups of 4 rows
    const int row0 = blockIdx.x * 32 + rg * 4;

    const float4* xp[4];
    #pragma unroll
    for (int r = 0; r < 4; ++r) {
        int row = row0 + r;
        if (row >= N_NODES) row = N_NODES - 1;   // clamp (loads only; store guarded)
        xp[r] = reinterpret_cast<const float4*>(x + (size_t)row * K_DIM);
    }

    float acc[4] = {0.f, 0.f, 0.f, 0.f};
    #pragma unroll 2
    for (int k4 = 0; k4 < K_DIM / 4; ++k4) {
        const int k = k4 * 4;
        const float w0 = wlds[(k + 0) * OUT_DIM + col];
        const float w1 = wlds[(k + 1) * OUT_DIM + col];
        const float w2 = wlds[(k + 2) * OUT_DIM + col];
        const float w3 = wlds[(k + 3) * OUT_DIM + col];
        #pragma unroll
        for (int r = 0; r < 4; ++r) {
            const float4 xv = xp[r][k4];
            acc[r] += xv.x * w0 + xv.y * w1 + xv.z * w2 + xv.w * w3;
        }
    }
    #pragma unroll
    for (int r = 0; r < 4; ++r) {
        const int row = row0 + r;
        if (row < N_NODES)
            h[(size_t)row * OUT_DIM + col] = __float2bfloat16(acc[r]);
    }
}

// -------- K2: scatter edges into fixed-stride windows; single LDS-atomic pass
__global__ __launch_bounds__(256) void fill_direct(const int*   __restrict__ esrc,
                                                   const int*   __restrict__ edst,
                                                   const float* __restrict__ ew,
                                                   int*         __restrict__ cursor,
                                                   uint64_t*    __restrict__ pairs) {
    __shared__ int cnt[NBKT];
    __shared__ int wbase[NBKT];
    const int t = threadIdx.x;
    for (int i = t; i < NBKT; i += 256) cnt[i] = 0;
    __syncthreads();

    uint32_t lo[AFIT], hi[AFIT];
    uint16_t rk[AFIT];                         // rank within block (< 4096)
    const int base = blockIdx.x * 256 * AFIT;
    #pragma unroll
    for (int k = 0; k < AFIT; ++k) {
        const int e = base + k * 256 + t;
        if (e < N_EDGES) {
            const uint32_t s = (uint32_t)esrc[e];
            const uint32_t d = (uint32_t)edst[e];
            lo[k] = (d << 16) | s;             // dst:16 | src:16
            hi[k] = __float_as_uint(ew[e]);
            rk[k] = (uint16_t)atomicAdd(&cnt[d >> 6], 1);   // count AND rank
        } else {
            lo[k] = 0xffffffffu;
        }
    }
    __syncthreads();
    for (int i = t; i < NBKT; i += 256) {
        const int c = cnt[i];
        if (c) wbase[i] = atomicAdd(&cursor[i], c);
    }
    __syncthreads();
    #pragma unroll
    for (int k = 0; k < AFIT; ++k) {
        if (lo[k] != 0xffffffffu) {
            const int b   = (int)(lo[k] >> 22);             // dst >> 6
            const int pos = wbase[b] + (int)rk[k];
            if (pos < CAP)                                  // overflow guard (P ~ 0)
                pairs[(size_t)b * CAP + pos] = ((uint64_t)hi[k] << 32) | lo[k];
        }
    }
}

// -------- K3: fused sort+pull per bucket (R12-proven) -----------------------
__global__ __launch_bounds__(512) void sort_pull(const int*      __restrict__ cursor,
                                                 const uint64_t* __restrict__ pairs,
                                                 const __hip_bfloat16* __restrict__ h,
                                                 float*          __restrict__ out) {
    __shared__ uint64_t stg[CAP];             // 24 KB
    __shared__ int lcnt[64];
    __shared__ int loff[65];
    const int b    = blockIdx.x;
    const int t    = threadIdx.x;
    const size_t beg = (size_t)b * CAP;
    const int cnt  = min(cursor[b], CAP);
    const int wv   = t >> 6;                  // 8 waves
    const int lane = t & 63;
    const int col  = lane & 31;
    const int half = lane >> 5;

    if (t < 64) lcnt[t] = 0;
    __syncthreads();

    for (int i = t; i < cnt; i += 512)
        atomicAdd(&lcnt[(int)((pairs[beg + i] >> 16) & 63)], 1);
    __syncthreads();
    if (t == 0) {
        int run = 0;
        #pragma unroll
        for (int i = 0; i < 64; ++i) { loff[i] = run; run += lcnt[i]; }
        loff[64] = run;
    }
    __syncthreads();
    if (t < 64) lcnt[t] = loff[t];            // cursor
    __syncthreads();
    for (int i = t; i < cnt; i += 512) {
        const uint64_t p = pairs[beg + i];
        const int pos = atomicAdd(&lcnt[(int)((p >> 16) & 63)], 1);
        stg[pos] = p;
    }
    __syncthreads();
    for (int nl = wv * 8; nl < wv * 8 + 8; ++nl) {
        const int node = (b << 6) + nl;
        if (node >= N_NODES) break;
        const int jb = loff[nl], je = loff[nl + 1];
        float acc = 0.f;
        int j = jb + half;
        for (; j + 6 < je; j += 8) {
            const uint64_t p0 = stg[j];
            const uint64_t p1 = stg[j + 2];
            const uint64_t p2 = stg[j + 4];
            const uint64_t p3 = stg[j + 6];
            const float a0 = __bfloat162float(h[(size_t)(p0 & 0xffffu) * OUT_DIM + col]);
            const float a1 = __bfloat162float(h[(size_t)(p1 & 0xffffu) * OUT_DIM + col]);
            const float a2 = __bfloat162float(h[(size_t)(p2 & 0xffffu) * OUT_DIM + col]);
            const float a3 = __bfloat162float(h[(size_t)(p3 & 0xffffu) * OUT_DIM + col]);
            acc += __uint_as_float((uint32_t)(p0 >> 32)) * a0;
            acc += __uint_as_float((uint32_t)(p1 >> 32)) * a1;
            acc += __uint_as_float((uint32_t)(p2 >> 32)) * a2;
            acc += __uint_as_float((uint32_t)(p3 >> 32)) * a3;
        }
        for (; j < je; j += 2) {
            const uint64_t p = stg[j];
            acc += __uint_as_float((uint32_t)(p >> 32)) *
                   __bfloat162float(h[(size_t)(p & 0xffffu) * OUT_DIM + col]);
        }
        acc += __shfl_xor(acc, 32, 64);
        if (half == 0) out[(size_t)node * OUT_DIM + col] = acc;
    }
}

// -------- fallback: atomic scatter (bf16 h) --------
__global__ __launch_bounds__(256) void scatter_kernel(const int*   __restrict__ esrc,
                                                      const int*   __restrict__ edst,
                                                      const float* __restrict__ ew,
                                                      const __hip_bfloat16* __restrict__ h,
                                                      float*       out) {
    const long long gid = (long long)blockIdx.x * blockDim.x + threadIdx.x;
    const int e   = (int)(gid >> 5);
    const int col = (int)(gid & 31);
    if (e >= N_EDGES) return;
    atomicAdd(out + (size_t)edst[e] * OUT_DIM + col,
              ew[e] * __bfloat162float(h[(size_t)esrc[e] * OUT_DIM + col]));
}

extern "C" void kernel_launch(void* const* d_in, const int* in_sizes, int n_in,
                              void* d_out, int out_size, void* d_ws, size_t ws_size,
                              hipStream_t stream) {
    const float* x    = (const float*)d_in[0];
    const float* w    = (const float*)d_in[1];
    const int*   esrc = (const int*)d_in[2];
    const int*   edst = (const int*)d_in[3];
    const float* ew   = (const float*)d_in[4];
    float*       out  = (float*)d_out;

    const size_t PAIRS_B = (size_t)NBKT * CAP * 8;         // 19,218,432
    const size_t H_B     = (size_t)N_NODES * OUT_DIM * 2;  //  3,200,000 (bf16)
    const size_t CUR_B   = (size_t)NBKT * 4;               //      3,128
    const size_t REQ     = PAIRS_B + H_B + CUR_B;

    uint64_t*        pairs  = (uint64_t*)d_ws;
    __hip_bfloat16*  h      = (__hip_bfloat16*)((char*)d_ws + PAIRS_B);
    int*             cursor = (int*)((char*)d_ws + PAIRS_B + H_B);

    if (ws_size >= REQ) {
        gemm_kernel<<<(N_NODES + 31) / 32, 256, 0, stream>>>(x, w, h, cursor);
        fill_direct<<<ABLK, 256, 0, stream>>>(esrc, edst, ew, cursor, pairs);
        sort_pull<<<NBKT, 512, 0, stream>>>(cursor, pairs, h, out);
    } else {
        __hip_bfloat16* hf = (__hip_bfloat16*)d_ws;
        int* cur = (int*)((char*)d_ws + H_B);
        (void)hipMemsetAsync(d_out, 0, (size_t)out_size * sizeof(float), stream);
        gemm_kernel<<<(N_NODES + 31) / 32, 256, 0, stream>>>(x, w, hf, cur);
        const long long total = (long long)N_EDGES * OUT_DIM;
        scatter_kernel<<<(int)((total + 255) / 256), 256, 0, stream>>>(esrc, edst, ew, hf, out);
    }
}

// Round 15
// 76.855 us; speedup vs baseline: 1.1193x; 1.0665x over previous
//
#include <hip/hip_runtime.h>
#include <hip/hip_bf16.h>
#include <stdint.h>

#define N_NODES   50000
#define K_DIM     128
#define OUT_DIM   32
#define N_EDGES   1600000
#define NBKT      782                         // 64-node coarse buckets
#define CAP       3072                        // fixed window stride (mean 2046 + 22 sigma)
#define AFIT      16                          // edges per thread in fill
#define FB        ((N_EDGES + 256*AFIT - 1) / (256*AFIT))   // 391 fill blocks
#define GB        ((N_NODES + 31) / 32)                     // 1563 gemm blocks

// -------- K0: zero the 782 bucket cursors (tiny) ----------------------------
__global__ __launch_bounds__(256) void zero_cursor(int* __restrict__ cursor) {
    for (int i = threadIdx.x; i < NBKT; i += 256) cursor[i] = 0;
}

// -------- K1: FUSED gemm + fill (data-independent roles, co-resident) -------
// blocks [0,FB): fill edges into fixed-stride bucket windows
// blocks [FB,FB+GB): h = x @ W -> bf16 (4 rows/thread, R14-proven)
__global__ __launch_bounds__(256) void gemm_fill(const float* __restrict__ x,
                                                 const float* __restrict__ w,
                                                 __hip_bfloat16* __restrict__ h,
                                                 const int*   __restrict__ esrc,
                                                 const int*   __restrict__ edst,
                                                 const float* __restrict__ ew,
                                                 int*         __restrict__ cursor,
                                                 uint64_t*    __restrict__ pairs) {
    __shared__ __align__(16) char smem[16384];
    const int t = threadIdx.x;

    if (blockIdx.x < FB) {
        // ---------------- fill role ----------------
        int* cnt   = (int*)smem;               // 782 ints
        int* wbase = ((int*)smem) + 1024;      // 782 ints at byte 4096
        for (int i = t; i < NBKT; i += 256) cnt[i] = 0;
        __syncthreads();

        uint32_t lo[AFIT], hi[AFIT];
        uint16_t rk[AFIT];
        const int base = blockIdx.x * 256 * AFIT;
        #pragma unroll
        for (int k = 0; k < AFIT; ++k) {
            const int e = base + k * 256 + t;
            if (e < N_EDGES) {
                const uint32_t s = (uint32_t)esrc[e];
                const uint32_t d = (uint32_t)edst[e];
                lo[k] = (d << 16) | s;         // dst:16 | src:16
                hi[k] = __float_as_uint(ew[e]);
                rk[k] = (uint16_t)atomicAdd(&cnt[d >> 6], 1);   // count AND rank
            } else {
                lo[k] = 0xffffffffu;
            }
        }
        __syncthreads();
        for (int i = t; i < NBKT; i += 256) {
            const int c = cnt[i];
            if (c) wbase[i] = atomicAdd(&cursor[i], c);
        }
        __syncthreads();
        #pragma unroll
        for (int k = 0; k < AFIT; ++k) {
            if (lo[k] != 0xffffffffu) {
                const int b   = (int)(lo[k] >> 22);             // dst >> 6
                const int pos = wbase[b] + (int)rk[k];
                if (pos < CAP)                                  // overflow guard (P ~ 0)
                    pairs[(size_t)b * CAP + pos] = ((uint64_t)hi[k] << 32) | lo[k];
            }
        }
    } else {
        // ---------------- gemm role ----------------
        float* wlds = (float*)smem;            // 128x32 fp32 = 16 KB
        #pragma unroll
        for (int i = 0; i < (K_DIM * OUT_DIM) / 256; ++i)
            wlds[i * 256 + t] = w[i * 256 + t];
        __syncthreads();

        const int col  = t & 31;
        const int rg   = t >> 5;               // 8 row-groups of 4 rows
        const int row0 = (blockIdx.x - FB) * 32 + rg * 4;

        const float4* xp[4];
        #pragma unroll
        for (int r = 0; r < 4; ++r) {
            int row = row0 + r;
            if (row >= N_NODES) row = N_NODES - 1;   // clamp (loads only)
            xp[r] = reinterpret_cast<const float4*>(x + (size_t)row * K_DIM);
        }

        float acc[4] = {0.f, 0.f, 0.f, 0.f};
        #pragma unroll 2
        for (int k4 = 0; k4 < K_DIM / 4; ++k4) {
            const int k = k4 * 4;
            const float w0 = wlds[(k + 0) * OUT_DIM + col];
            const float w1 = wlds[(k + 1) * OUT_DIM + col];
            const float w2 = wlds[(k + 2) * OUT_DIM + col];
            const float w3 = wlds[(k + 3) * OUT_DIM + col];
            #pragma unroll
            for (int r = 0; r < 4; ++r) {
                const float4 xv = xp[r][k4];
                acc[r] += xv.x * w0 + xv.y * w1 + xv.z * w2 + xv.w * w3;
            }
        }
        #pragma unroll
        for (int r = 0; r < 4; ++r) {
            const int row = row0 + r;
            if (row < N_NODES)
                h[(size_t)row * OUT_DIM + col] = __float2bfloat16(acc[r]);
        }
    }
}

// -------- K2: sort+pull v3 — single pairs read, rank from first LDS pass ----
__global__ __launch_bounds__(512) void sort_pull(const int*      __restrict__ cursor,
                                                 const uint64_t* __restrict__ pairs,
                                                 const __hip_bfloat16* __restrict__ h,
                                                 float*          __restrict__ out) {
    __shared__ uint64_t stg[CAP];             // 24 KB
    __shared__ int lcnt[64];
    __shared__ int loff[65];
    const int b    = blockIdx.x;
    const int t    = threadIdx.x;
    const size_t beg = (size_t)b * CAP;
    const int cnt  = min(cursor[b], CAP);
    const int wv   = t >> 6;                  // 8 waves
    const int lane = t & 63;
    const int col  = lane & 31;
    const int half = lane >> 5;

    if (t < 64) lcnt[t] = 0;
    __syncthreads();

    // single coalesced read + rank capture (static 6-slot unroll: CAP = 6*512)
    uint64_t pl[6];
    int      pr[6];                           // (node<<12)|rank, or -1
    #pragma unroll
    for (int k = 0; k < 6; ++k) {
        const int i = t + k * 512;
        if (i < cnt) {
            const uint64_t p = pairs[beg + i];
            const int nl = (int)((p >> 16) & 63);
            pl[k] = p;
            pr[k] = (nl << 12) | atomicAdd(&lcnt[nl], 1);
        } else {
            pr[k] = -1;
        }
    }
    __syncthreads();
    if (t == 0) {
        int run = 0;
        #pragma unroll
        for (int i = 0; i < 64; ++i) { loff[i] = run; run += lcnt[i]; }
        loff[64] = run;
    }
    __syncthreads();
    #pragma unroll
    for (int k = 0; k < 6; ++k) {
        if (pr[k] >= 0)
            stg[loff[pr[k] >> 12] + (pr[k] & 0xfff)] = pl[k];
    }
    __syncthreads();

    // pull: wave wv owns local nodes wv*8..wv*8+7 (R12-proven body)
    for (int nl = wv * 8; nl < wv * 8 + 8; ++nl) {
        const int node = (b << 6) + nl;
        if (node >= N_NODES) break;
        const int jb = loff[nl], je = loff[nl + 1];
        float acc = 0.f;
        int j = jb + half;
        for (; j + 6 < je; j += 8) {
            const uint64_t p0 = stg[j];
            const uint64_t p1 = stg[j + 2];
            const uint64_t p2 = stg[j + 4];
            const uint64_t p3 = stg[j + 6];
            const float a0 = __bfloat162float(h[(size_t)(p0 & 0xffffu) * OUT_DIM + col]);
            const float a1 = __bfloat162float(h[(size_t)(p1 & 0xffffu) * OUT_DIM + col]);
            const float a2 = __bfloat162float(h[(size_t)(p2 & 0xffffu) * OUT_DIM + col]);
            const float a3 = __bfloat162float(h[(size_t)(p3 & 0xffffu) * OUT_DIM + col]);
            acc += __uint_as_float((uint32_t)(p0 >> 32)) * a0;
            acc += __uint_as_float((uint32_t)(p1 >> 32)) * a1;
            acc += __uint_as_float((uint32_t)(p2 >> 32)) * a2;
            acc += __uint_as_float((uint32_t)(p3 >> 32)) * a3;
        }
        for (; j < je; j += 2) {
            const uint64_t p = stg[j];
            acc += __uint_as_float((uint32_t)(p >> 32)) *
                   __bfloat162float(h[(size_t)(p & 0xffffu) * OUT_DIM + col]);
        }
        acc += __shfl_xor(acc, 32, 64);
        if (half == 0) out[(size_t)node * OUT_DIM + col] = acc;
    }
}

// -------- fallback path kernels (ws too small): plain gemm + atomic scatter -
__global__ __launch_bounds__(256) void gemm_only(const float* __restrict__ x,
                                                 const float* __restrict__ w,
                                                 __hip_bfloat16* __restrict__ h) {
    __shared__ float wlds[K_DIM * OUT_DIM];
    const int t = threadIdx.x;
    #pragma unroll
    for (int i = 0; i < (K_DIM * OUT_DIM) / 256; ++i)
        wlds[i * 256 + t] = w[i * 256 + t];
    __syncthreads();
    const int row = blockIdx.x * 8 + (t >> 5);
    const int col = t & 31;
    if (row >= N_NODES) return;
    const float4* x4 = reinterpret_cast<const float4*>(x + (size_t)row * K_DIM);
    float acc = 0.f;
    #pragma unroll
    for (int k4 = 0; k4 < K_DIM / 4; ++k4) {
        float4 xv = x4[k4];
        const int k = k4 * 4;
        acc += xv.x * wlds[(k + 0) * OUT_DIM + col] + xv.y * wlds[(k + 1) * OUT_DIM + col]
             + xv.z * wlds[(k + 2) * OUT_DIM + col] + xv.w * wlds[(k + 3) * OUT_DIM + col];
    }
    h[(size_t)row * OUT_DIM + col] = __float2bfloat16(acc);
}

__global__ __launch_bounds__(256) void scatter_kernel(const int*   __restrict__ esrc,
                                                      const int*   __restrict__ edst,
                                                      const float* __restrict__ ew,
                                                      const __hip_bfloat16* __restrict__ h,
                                                      float*       out) {
    const long long gid = (long long)blockIdx.x * blockDim.x + threadIdx.x;
    const int e   = (int)(gid >> 5);
    const int col = (int)(gid & 31);
    if (e >= N_EDGES) return;
    atomicAdd(out + (size_t)edst[e] * OUT_DIM + col,
              ew[e] * __bfloat162float(h[(size_t)esrc[e] * OUT_DIM + col]));
}

extern "C" void kernel_launch(void* const* d_in, const int* in_sizes, int n_in,
                              void* d_out, int out_size, void* d_ws, size_t ws_size,
                              hipStream_t stream) {
    const float* x    = (const float*)d_in[0];
    const float* w    = (const float*)d_in[1];
    const int*   esrc = (const int*)d_in[2];
    const int*   edst = (const int*)d_in[3];
    const float* ew   = (const float*)d_in[4];
    float*       out  = (float*)d_out;

    const size_t PAIRS_B = (size_t)NBKT * CAP * 8;         // 19,218,432
    const size_t H_B     = (size_t)N_NODES * OUT_DIM * 2;  //  3,200,000 (bf16)
    const size_t CUR_B   = (size_t)NBKT * 4;               //      3,128
    const size_t REQ     = PAIRS_B + H_B + CUR_B;

    uint64_t*        pairs  = (uint64_t*)d_ws;
    __hip_bfloat16*  h      = (__hip_bfloat16*)((char*)d_ws + PAIRS_B);
    int*             cursor = (int*)((char*)d_ws + PAIRS_B + H_B);

    if (ws_size >= REQ) {
        zero_cursor<<<1, 256, 0, stream>>>(cursor);
        gemm_fill<<<FB + GB, 256, 0, stream>>>(x, w, h, esrc, edst, ew, cursor, pairs);
        sort_pull<<<NBKT, 512, 0, stream>>>(cursor, pairs, h, out);
    } else {
        __hip_bfloat16* hf = (__hip_bfloat16*)d_ws;
        (void)hipMemsetAsync(d_out, 0, (size_t)out_size * sizeof(float), stream);
        gemm_only<<<(N_NODES + 7) / 8, 256, 0, stream>>>(x, w, hf);
        const long long total = (long long)N_EDGES * OUT_DIM;
        scatter_kernel<<<(int)((total + 255) / 256), 256, 0, stream>>>(esrc, edst, ew, hf, out);
    }
}

// Round 16
// 66.886 us; speedup vs baseline: 1.2861x; 1.1490x over previous
//
#include <hip/hip_runtime.h>
#include <hip/hip_bf16.h>
#include <stdint.h>

#define N_NODES   50000
#define K_DIM     128
#define OUT_DIM   32
#define N_EDGES   1600000
#define NBKT      782                         // 64-node coarse buckets
#define CAP       3072                        // fixed window stride (mean 2046 + 22 sigma)
#define AFIT      16                          // edges per thread in fill
#define FB        ((N_EDGES + 256*AFIT - 1) / (256*AFIT))   // 391 fill blocks
#define GB        ((N_NODES + 31) / 32)                     // 1563 gemm blocks

// -------- K0: zero the 782 bucket cursors (tiny) ----------------------------
__global__ __launch_bounds__(256) void zero_cursor(int* __restrict__ cursor) {
    for (int i = threadIdx.x; i < NBKT; i += 256) cursor[i] = 0;
}

// -------- K1: FUSED gemm + fill (data-independent roles, co-resident) -------
// blocks [0,FB): fill edges into fixed-stride bucket windows
// blocks [FB,FB+GB): h = x @ W -> bf16, x-tile STAGED IN LDS (coalesced)
__global__ __launch_bounds__(256) void gemm_fill(const float* __restrict__ x,
                                                 const float* __restrict__ w,
                                                 __hip_bfloat16* __restrict__ h,
                                                 const int*   __restrict__ esrc,
                                                 const int*   __restrict__ edst,
                                                 const float* __restrict__ ew,
                                                 int*         __restrict__ cursor,
                                                 uint64_t*    __restrict__ pairs) {
    __shared__ __align__(16) char smem[32768];
    const int t = threadIdx.x;

    if (blockIdx.x < FB) {
        // ---------------- fill role (8 KB of smem) ----------------
        int* cnt   = (int*)smem;               // 782 ints
        int* wbase = ((int*)smem) + 1024;      // 782 ints
        for (int i = t; i < NBKT; i += 256) cnt[i] = 0;
        __syncthreads();

        uint32_t lo[AFIT], hi[AFIT];
        uint16_t rk[AFIT];
        const int base = blockIdx.x * 256 * AFIT;
        #pragma unroll
        for (int k = 0; k < AFIT; ++k) {
            const int e = base + k * 256 + t;
            if (e < N_EDGES) {
                const uint32_t s = (uint32_t)esrc[e];
                const uint32_t d = (uint32_t)edst[e];
                lo[k] = (d << 16) | s;         // dst:16 | src:16
                hi[k] = __float_as_uint(ew[e]);
                rk[k] = (uint16_t)atomicAdd(&cnt[d >> 6], 1);   // count AND rank
            } else {
                lo[k] = 0xffffffffu;
            }
        }
        __syncthreads();
        for (int i = t; i < NBKT; i += 256) {
            const int c = cnt[i];
            if (c) wbase[i] = atomicAdd(&cursor[i], c);
        }
        __syncthreads();
        #pragma unroll
        for (int k = 0; k < AFIT; ++k) {
            if (lo[k] != 0xffffffffu) {
                const int b   = (int)(lo[k] >> 22);             // dst >> 6
                const int pos = wbase[b] + (int)rk[k];
                if (pos < CAP)                                  // overflow guard (P ~ 0)
                    pairs[(size_t)b * CAP + pos] = ((uint64_t)hi[k] << 32) | lo[k];
            }
        }
    } else {
        // ---------------- gemm role (32 KB of smem) ----------------
        float*  wlds = (float*)smem;                    // 128x32 f32 = 16 KB
        float4* wl4  = (float4*)smem;
        float4* xl4  = (float4*)(smem + 16384);         // 32 rows x 128 f32 = 16 KB

        // stage W: 1024 float4, coalesced
        const float4* wg4 = reinterpret_cast<const float4*>(w);
        #pragma unroll
        for (int i = 0; i < 4; ++i) wl4[i * 256 + t] = wg4[i * 256 + t];

        // stage x tile: rows row0..row0+31 = 1024 contiguous float4, coalesced
        const int row0 = (blockIdx.x - FB) * 32;
        const long long gbase4 = (long long)row0 * (K_DIM / 4);
        const long long gmax4  = (long long)N_NODES * (K_DIM / 4);
        const float4* xg4 = reinterpret_cast<const float4*>(x);
        #pragma unroll
        for (int i = 0; i < 4; ++i) {
            const int idx = i * 256 + t;
            const long long gi = gbase4 + idx;
            xl4[idx] = (gi < gmax4) ? xg4[gi]
                                    : make_float4(0.f, 0.f, 0.f, 0.f);
        }
        __syncthreads();

        const int col = t & 31;
        const int rg  = t >> 5;                // 8 row-groups of 4 rows

        float acc[4] = {0.f, 0.f, 0.f, 0.f};
        #pragma unroll 4
        for (int k4 = 0; k4 < K_DIM / 4; ++k4) {
            const int k = k4 * 4;
            const float w0 = wlds[(k + 0) * OUT_DIM + col];
            const float w1 = wlds[(k + 1) * OUT_DIM + col];
            const float w2 = wlds[(k + 2) * OUT_DIM + col];
            const float w3 = wlds[(k + 3) * OUT_DIM + col];
            #pragma unroll
            for (int r = 0; r < 4; ++r) {
                const float4 xv = xl4[(rg * 4 + r) * (K_DIM / 4) + k4];
                acc[r] += xv.x * w0 + xv.y * w1 + xv.z * w2 + xv.w * w3;
            }
        }
        #pragma unroll
        for (int r = 0; r < 4; ++r) {
            const int row = row0 + rg * 4 + r;
            if (row < N_NODES)
                h[(size_t)row * OUT_DIM + col] = __float2bfloat16(acc[r]);
        }
    }
}

// -------- K2: sort+pull v3 — single pairs read, rank from first LDS pass ----
__global__ __launch_bounds__(512) void sort_pull(const int*      __restrict__ cursor,
                                                 const uint64_t* __restrict__ pairs,
                                                 const __hip_bfloat16* __restrict__ h,
                                                 float*          __restrict__ out) {
    __shared__ uint64_t stg[CAP];             // 24 KB
    __shared__ int lcnt[64];
    __shared__ int loff[65];
    const int b    = blockIdx.x;
    const int t    = threadIdx.x;
    const size_t beg = (size_t)b * CAP;
    const int cnt  = min(cursor[b], CAP);
    const int wv   = t >> 6;                  // 8 waves
    const int lane = t & 63;
    const int col  = lane & 31;
    const int half = lane >> 5;

    if (t < 64) lcnt[t] = 0;
    __syncthreads();

    // single coalesced read + rank capture (static 6-slot unroll: CAP = 6*512)
    uint64_t pl[6];
    int      pr[6];                           // (node<<12)|rank, or -1
    #pragma unroll
    for (int k = 0; k < 6; ++k) {
        const int i = t + k * 512;
        if (i < cnt) {
            const uint64_t p = pairs[beg + i];
            const int nl = (int)((p >> 16) & 63);
            pl[k] = p;
            pr[k] = (nl << 12) | atomicAdd(&lcnt[nl], 1);
        } else {
            pr[k] = -1;
        }
    }
    __syncthreads();
    if (t == 0) {
        int run = 0;
        #pragma unroll
        for (int i = 0; i < 64; ++i) { loff[i] = run; run += lcnt[i]; }
        loff[64] = run;
    }
    __syncthreads();
    #pragma unroll
    for (int k = 0; k < 6; ++k) {
        if (pr[k] >= 0)
            stg[loff[pr[k] >> 12] + (pr[k] & 0xfff)] = pl[k];
    }
    __syncthreads();

    // pull: wave wv owns local nodes wv*8..wv*8+7
    for (int nl = wv * 8; nl < wv * 8 + 8; ++nl) {
        const int node = (b << 6) + nl;
        if (node >= N_NODES) break;
        const int jb = loff[nl], je = loff[nl + 1];
        float acc = 0.f;
        int j = jb + half;
        for (; j + 6 < je; j += 8) {
            const uint64_t p0 = stg[j];
            const uint64_t p1 = stg[j + 2];
            const uint64_t p2 = stg[j + 4];
            const uint64_t p3 = stg[j + 6];
            const float a0 = __bfloat162float(h[(size_t)(p0 & 0xffffu) * OUT_DIM + col]);
            const float a1 = __bfloat162float(h[(size_t)(p1 & 0xffffu) * OUT_DIM + col]);
            const float a2 = __bfloat162float(h[(size_t)(p2 & 0xffffu) * OUT_DIM + col]);
            const float a3 = __bfloat162float(h[(size_t)(p3 & 0xffffu) * OUT_DIM + col]);
            acc += __uint_as_float((uint32_t)(p0 >> 32)) * a0;
            acc += __uint_as_float((uint32_t)(p1 >> 32)) * a1;
            acc += __uint_as_float((uint32_t)(p2 >> 32)) * a2;
            acc += __uint_as_float((uint32_t)(p3 >> 32)) * a3;
        }
        for (; j < je; j += 2) {
            const uint64_t p = stg[j];
            acc += __uint_as_float((uint32_t)(p >> 32)) *
                   __bfloat162float(h[(size_t)(p & 0xffffu) * OUT_DIM + col]);
        }
        acc += __shfl_xor(acc, 32, 64);
        if (half == 0) out[(size_t)node * OUT_DIM + col] = acc;
    }
}

// -------- fallback path kernels (ws too small): plain gemm + atomic scatter -
__global__ __launch_bounds__(256) void gemm_only(const float* __restrict__ x,
                                                 const float* __restrict__ w,
                                                 __hip_bfloat16* __restrict__ h) {
    __shared__ float wlds[K_DIM * OUT_DIM];
    const int t = threadIdx.x;
    #pragma unroll
    for (int i = 0; i < (K_DIM * OUT_DIM) / 256; ++i)
        wlds[i * 256 + t] = w[i * 256 + t];
    __syncthreads();
    const int row = blockIdx.x * 8 + (t >> 5);
    const int col = t & 31;
    if (row >= N_NODES) return;
    const float4* x4 = reinterpret_cast<const float4*>(x + (size_t)row * K_DIM);
    float acc = 0.f;
    #pragma unroll
    for (int k4 = 0; k4 < K_DIM / 4; ++k4) {
        float4 xv = x4[k4];
        const int k = k4 * 4;
        acc += xv.x * wlds[(k + 0) * OUT_DIM + col] + xv.y * wlds[(k + 1) * OUT_DIM + col]
             + xv.z * wlds[(k + 2) * OUT_DIM + col] + xv.w * wlds[(k + 3) * OUT_DIM + col];
    }
    h[(size_t)row * OUT_DIM + col] = __float2bfloat16(acc);
}

__global__ __launch_bounds__(256) void scatter_kernel(const int*   __restrict__ esrc,
                                                      const int*   __restrict__ edst,
                                                      const float* __restrict__ ew,
                                                      const __hip_bfloat16* __restrict__ h,
                                                      float*       out) {
    const long long gid = (long long)blockIdx.x * blockDim.x + threadIdx.x;
    const int e   = (int)(gid >> 5);
    const int col = (int)(gid & 31);
    if (e >= N_EDGES) return;
    atomicAdd(out + (size_t)edst[e] * OUT_DIM + col,
              ew[e] * __bfloat162float(h[(size_t)esrc[e] * OUT_DIM + col]));
}

extern "C" void kernel_launch(void* const* d_in, const int* in_sizes, int n_in,
                              void* d_out, int out_size, void* d_ws, size_t ws_size,
                              hipStream_t stream) {
    const float* x    = (const float*)d_in[0];
    const float* w    = (const float*)d_in[1];
    const int*   esrc = (const int*)d_in[2];
    const int*   edst = (const int*)d_in[3];
    const float* ew   = (const float*)d_in[4];
    float*       out  = (float*)d_out;

    const size_t PAIRS_B = (size_t)NBKT * CAP * 8;         // 19,218,432
    const size_t H_B     = (size_t)N_NODES * OUT_DIM * 2;  //  3,200,000 (bf16)
    const size_t CUR_B   = (size_t)NBKT * 4;               //      3,128
    const size_t REQ     = PAIRS_B + H_B + CUR_B;

    uint64_t*        pairs  = (uint64_t*)d_ws;
    __hip_bfloat16*  h      = (__hip_bfloat16*)((char*)d_ws + PAIRS_B);
    int*             cursor = (int*)((char*)d_ws + PAIRS_B + H_B);

    if (ws_size >= REQ) {
        zero_cursor<<<1, 256, 0, stream>>>(cursor);
        gemm_fill<<<FB + GB, 256, 0, stream>>>(x, w, h, esrc, edst, ew, cursor, pairs);
        sort_pull<<<NBKT, 512, 0, stream>>>(cursor, pairs, h, out);
    } else {
        __hip_bfloat16* hf = (__hip_bfloat16*)d_ws;
        (void)hipMemsetAsync(d_out, 0, (size_t)out_size * sizeof(float), stream);
        gemm_only<<<(N_NODES + 7) / 8, 256, 0, stream>>>(x, w, hf);
        const long long total = (long long)N_EDGES * OUT_DIM;
        scatter_kernel<<<(int)((total + 255) / 256), 256, 0, stream>>>(esrc, edst, ew, hf, out);
    }
}